// Round 1
// baseline (513.526 us; speedup 1.0000x reference)
//
#include <hip/hip_runtime.h>

typedef __bf16 bf16x8 __attribute__((ext_vector_type(8)));
typedef float f32x4 __attribute__((ext_vector_type(4)));

union BF8 { unsigned short u[8]; bf16x8 v; };

__device__ __forceinline__ unsigned short f2bf(float f){
  unsigned int u = __float_as_uint(f);
  return (unsigned short)((u + 0x7fffu + ((u >> 16) & 1u)) >> 16);
}

__device__ __forceinline__ bf16x8 load_w8(const float* __restrict__ p){
  const float4 a = *(const float4*)p;
  const float4 b = *(const float4*)(p + 4);
  BF8 r;
  r.u[0]=f2bf(a.x); r.u[1]=f2bf(a.y); r.u[2]=f2bf(a.z); r.u[3]=f2bf(a.w);
  r.u[4]=f2bf(b.x); r.u[5]=f2bf(b.y); r.u[6]=f2bf(b.z); r.u[7]=f2bf(b.w);
  return r.v;
}

__device__ __forceinline__ float sigm(float x){ return 1.f/(1.f + __expf(-x)); }
__device__ __forceinline__ float tanh_(float x){ return 2.f/(1.f + __expf(-2.f*x)) - 1.f; }

// Grid: 256 blocks x 256 threads (4 waves). Block b owns batch rows [16b, 16b+16).
// Wave w owns hidden cols [16w, 16w+16) for h_inter/c_inter and for all 4 gates.
// State layout in LDS: s_h/s_c [col16][row16][hid64] bf16, XOR-swizzled so the
// MFMA A-fragment ds_read_b128 (rows 0..15 at one k-slice) is ~2-way conflict.
__global__ __launch_bounds__(256) void lstm2d_kernel(
    const float* __restrict__ x,   const float* __restrict__ Wx,
    const float* __restrict__ Wh,  const float* __restrict__ Wh2,
    const float* __restrict__ Wih, const float* __restrict__ Whh,
    const float* __restrict__ bih, const float* __restrict__ bhh,
    const float* __restrict__ Wfc, const float* __restrict__ bfc,
    float* __restrict__ out)
{
  __shared__ __align__(16) unsigned short s_h[16*16*64];   // 32 KB
  __shared__ __align__(16) unsigned short s_c[16*16*64];   // 32 KB
  __shared__ __align__(16) unsigned short s_hint[16*64];   // 2 KB (h_inter bf16)
  __shared__ float s_x[16*256];                            // 16 KB  [row][i][c]
  __shared__ float s_logit[128];                           // [wave][row][m]

  const int tid  = threadIdx.x;
  const int w    = tid >> 6;     // wave 0..3
  const int lane = tid & 63;
  const int l16  = lane & 15;
  const int g4   = lane >> 4;    // 0..3
  const int g8   = g4 * 8;

  // ---- stage x (coalesced) ----
  const float* xg = x + blockIdx.x * 4096;
  #pragma unroll
  for (int it=0; it<16; ++it) s_x[tid + it*256] = xg[tid + it*256];
  // ---- zero h/c state ----
  unsigned int* zh = (unsigned int*)s_h;
  unsigned int* zc = (unsigned int*)s_c;
  #pragma unroll
  for (int it=0; it<32; ++it){ zh[tid + it*256] = 0u; zc[tid + it*256] = 0u; }

  // ---- B-operand weight fragments, cached in VGPRs for all 256 cells ----
  // B[k][n] = W[n][k]; frag(s): lane holds W[n][k0..k0+7], n = tile*16 + l16,
  // k0 = s*32 + g4*8  (gfx950 16x16x32 B layout: col=lane%16, k=(lane/16)*8+e)
  bf16x8 bh[4], bc[4], bg[4][2];
  #pragma unroll
  for (int s=0;s<4;++s){
    const int n = w*16 + l16, k = s*32 + g8;
    bh[s] = load_w8(Wh  + n*128 + k);   // K=128: [h_prev | h_up]
    bc[s] = load_w8(Wh2 + n*128 + k);
  }
  #pragma unroll
  for (int g=0; g<4; ++g){
    #pragma unroll
    for (int s=0;s<2;++s){
      const int n = g*64 + w*16 + l16, k = s*32 + g8;
      bg[g][s] = load_w8(Whh + n*64 + k);  // K=64: h_inter
    }
  }

  const float wx0 = Wx[0], wx1 = Wx[1];
  const float bfc0 = bfc[0], bfc1 = bfc[1];
  // gates = h_inter@Whh.T + xh*(Wih[:,0]-Wih[:,1]) + (Wih[:,1]+bih+bhh)
  float base_[4], dvec_[4];
  #pragma unroll
  for (int g=0; g<4; ++g){
    const int cg = g*64 + w*16 + l16;
    base_[g] = bih[cg] + bhh[cg] + Wih[cg*2+1];
    dvec_[g] = Wih[cg*2+0] - Wih[cg*2+1];
  }
  const int colw = w*16 + l16;
  const float wf0 = Wfc[colw], wf1 = Wfc[64 + colw];

  float lp = 0.f;
  int aa = 0;
  int pi = 0, pc = 0;   // previous cell (row, col), wave-uniform

  __syncthreads();

  for (int tl = 0; tl < 256; ++tl){
    const int i = tl >> 4, t = tl & 15;
    const int c  = (i & 1) ? (15 - t) : t;        // grid col of this cell
    const int cp = (i & 1) ? (16 - t) : (t - 1);  // grid col of prev traversal cell

    // ---------- phase 1: h_inter / c_inter (K=128 over [prev|up]) ----------
    f32x4 aH = {0.f,0.f,0.f,0.f}, aC = {0.f,0.f,0.f,0.f};
    if (t > 0){   // h_prev/c_prev half (zeros at row start)
      #pragma unroll
      for (int s=0;s<2;++s){
        const int off = cp*1024 + l16*64 + ((s*32 + g8) ^ ((l16 & 7) << 3));
        bf16x8 ah = *(const bf16x8*)(s_h + off);
        bf16x8 ac = *(const bf16x8*)(s_c + off);
        aH = __builtin_amdgcn_mfma_f32_16x16x32_bf16(ah, bh[s], aH, 0,0,0);
        aC = __builtin_amdgcn_mfma_f32_16x16x32_bf16(ac, bc[s], aC, 0,0,0);
      }
    }
    #pragma unroll
    for (int s=0;s<2;++s){    // h_up/c_up half (state[c] = row above, zeros at row 0)
      const int off = c*1024 + l16*64 + ((s*32 + g8) ^ ((l16 & 7) << 3));
      bf16x8 ah = *(const bf16x8*)(s_h + off);
      bf16x8 ac = *(const bf16x8*)(s_c + off);
      aH = __builtin_amdgcn_mfma_f32_16x16x32_bf16(ah, bh[s+2], aH, 0,0,0);
      aC = __builtin_amdgcn_mfma_f32_16x16x32_bf16(ac, bc[s+2], aC, 0,0,0);
    }

    // gate accumulator init: base + xh*dvec (folds emb@Wih.T + biases)
    f32x4 accG[4];
    #pragma unroll
    for (int r=0;r<4;++r){
      const int row = g4*4 + r;
      const float xp = (t > 0) ? s_x[row*256 + i*16 + cp] : 0.f;
      const float xu = (i > 0) ? s_x[row*256 + (i-1)*16 + c] : 0.f;
      const float xh = (xp*wx0 + xu*wx1 + 1.f) * 0.5f;
      #pragma unroll
      for (int g=0; g<4; ++g) accG[g][r] = base_[g] + xh * dvec_[g];
    }

    // wave0 lanes 0..15: finish PREVIOUS cell's log-softmax + lp accumulation
    if (w == 0 && lane < 16 && tl > 0){
      float l0 = bfc0, l1 = bfc1;
      #pragma unroll
      for (int ww=0; ww<4; ++ww){
        l0 += s_logit[(ww*16 + lane)*2 + 0];
        l1 += s_logit[(ww*16 + lane)*2 + 1];
      }
      const float mx  = fmaxf(l0, l1);
      const float lse = mx + __logf(__expf(l0-mx) + __expf(l1-mx));
      const float xv  = s_x[lane*256 + pi*16 + pc];
      const int   msk = xv > 0.f;
      lp += msk ? (l0 - lse) : (l1 - lse);
      aa += msk;
    }

    // hand off h_inter as bf16 (swizzled) for the gates GEMM A-operand
    #pragma unroll
    for (int r=0;r<4;++r){
      const int row = g4*4 + r;
      s_hint[row*64 + (colw ^ ((row & 7) << 3))] = f2bf(aH[r]);
    }

    __syncthreads();

    // ---------- phase 2: gates GEMM + epilogue ----------
    #pragma unroll
    for (int s=0;s<2;++s){
      const int off = l16*64 + ((s*32 + g8) ^ ((l16 & 7) << 3));
      bf16x8 ag = *(const bf16x8*)(s_hint + off);
      #pragma unroll
      for (int g=0; g<4; ++g)
        accG[g] = __builtin_amdgcn_mfma_f32_16x16x32_bf16(ag, bg[g][s], accG[g], 0,0,0);
    }

    // activations: c_inter (aC) is already in this wave's registers, same (row,col)
    float p0[4], p1[4];
    #pragma unroll
    for (int r=0;r<4;++r){
      const int row = g4*4 + r;
      const float ig = accG[0][r], fg = accG[1][r], gg = accG[2][r], og = accG[3][r];
      const float cn = sigm(fg)*aC[r] + sigm(ig)*tanh_(gg);
      const float hn = sigm(og)*tanh_(cn);
      const int se = c*1024 + row*64 + (colw ^ ((row & 7) << 3));
      s_h[se] = f2bf(hn);
      s_c[se] = f2bf(cn);
      p0[r] = hn * wf0;
      p1[r] = hn * wf1;
    }

    // per-wave partial logits: reduce over the 16 lanes of each row-group
    #pragma unroll
    for (int off=1; off<16; off<<=1){
      #pragma unroll
      for (int r=0;r<4;++r){
        p0[r] += __shfl_xor(p0[r], off);
        p1[r] += __shfl_xor(p1[r], off);
      }
    }
    if (l16 == 0){
      #pragma unroll
      for (int r=0;r<4;++r){
        const int row = g4*4 + r;
        s_logit[(w*16 + row)*2 + 0] = p0[r];
        s_logit[(w*16 + row)*2 + 1] = p1[r];
      }
    }

    pi = i; pc = c;
    __syncthreads();
  }

  // finish last cell (row 15, col 0 -- the final traversal cell), rec fix, store
  if (w == 0 && lane < 16){
    float l0 = bfc0, l1 = bfc1;
    #pragma unroll
    for (int ww=0; ww<4; ++ww){
      l0 += s_logit[(ww*16 + lane)*2 + 0];
      l1 += s_logit[(ww*16 + lane)*2 + 1];
    }
    const float mx  = fmaxf(l0, l1);
    const float lse = mx + __logf(__expf(l0-mx) + __expf(l1-mx));
    const float xv  = s_x[lane*256 + 15*16 + 0];
    const int   msk = xv > 0.f;
    const float contrib = msk ? (l0 - lse) : (l1 - lse);
    lp += contrib; aa += msk;
    if (aa == 1 && msk) lp -= contrib;   // factor = 1 - mask[15,0] when aa==1
    out[blockIdx.x*16 + lane] = lp;
  }
}

extern "C" void kernel_launch(void* const* d_in, const int* in_sizes, int n_in,
                              void* d_out, int out_size, void* d_ws, size_t ws_size,
                              hipStream_t stream) {
  const float* x   = (const float*)d_in[0];
  const float* Wx  = (const float*)d_in[1];
  const float* Wh  = (const float*)d_in[2];
  const float* Wh2 = (const float*)d_in[3];
  const float* Wih = (const float*)d_in[4];
  const float* Whh = (const float*)d_in[5];
  const float* bih = (const float*)d_in[6];
  const float* bhh = (const float*)d_in[7];
  const float* Wfc = (const float*)d_in[8];
  const float* bfc = (const float*)d_in[9];
  float* out = (float*)d_out;
  lstm2d_kernel<<<dim3(256), dim3(256), 0, stream>>>(
      x, Wx, Wh, Wh2, Wih, Whh, bih, bhh, Wfc, bfc, out);
}

// Round 2
// 443.749 us; speedup vs baseline: 1.1572x; 1.1572x over previous
//
#include <hip/hip_runtime.h>

typedef __bf16 bf16x8 __attribute__((ext_vector_type(8)));
typedef float f32x4 __attribute__((ext_vector_type(4)));

union BF8 { unsigned short u[8]; bf16x8 v; };

__device__ __forceinline__ unsigned short f2bf(float f){
  unsigned int u = __float_as_uint(f);
  return (unsigned short)((u + 0x7fffu + ((u >> 16) & 1u)) >> 16);
}

__device__ __forceinline__ bf16x8 load_w8(const float* __restrict__ p){
  const float4 a = *(const float4*)p;
  const float4 b = *(const float4*)(p + 4);
  BF8 r;
  r.u[0]=f2bf(a.x); r.u[1]=f2bf(a.y); r.u[2]=f2bf(a.z); r.u[3]=f2bf(a.w);
  r.u[4]=f2bf(b.x); r.u[5]=f2bf(b.y); r.u[6]=f2bf(b.z); r.u[7]=f2bf(b.w);
  return r.v;
}

__device__ __forceinline__ float sigm(float x){ return 1.f/(1.f + __expf(-x)); }
__device__ __forceinline__ float tanh_(float x){ return 2.f/(1.f + __expf(-2.f*x)) - 1.f; }

#define MFMA(a,b,c) __builtin_amdgcn_mfma_f32_16x16x32_bf16((a),(b),(c),0,0,0)

// 256 blocks x 256 threads (4 waves, 1 wave/SIMD). Block owns 16 batch rows.
// Wave w owns hidden cols [16w,16w+16). State s_h/s_c: [col16][batch16][hid64]
// bf16, XOR-swizzled (hid ^ ((batch&7)<<3)) for ~conflict-free ds_read_b128.
// Serial chain per cell: h_prev GEMM -> h_inter handoff -> gates GEMM ->
// activations -> state write. Up-row GEMM contributions are prefetched one
// slot ahead (they only read the previous row's columns).
__global__ __launch_bounds__(256,1) void lstm2d_kernel(
    const float* __restrict__ x,   const float* __restrict__ Wx,
    const float* __restrict__ Wh,  const float* __restrict__ Wh2,
    const float* __restrict__ Wih, const float* __restrict__ Whh,
    const float* __restrict__ bih, const float* __restrict__ bhh,
    const float* __restrict__ Wfc, const float* __restrict__ bfc,
    float* __restrict__ out)
{
  __shared__ __align__(16) unsigned short s_h[16*16*64];   // 32 KB
  __shared__ __align__(16) unsigned short s_c[16*16*64];   // 32 KB
  __shared__ __align__(16) unsigned short s_hint[16*64];   // 2 KB
  __shared__ __align__(16) float s_xh[256*16];             // 16 KB [slot][row]
  __shared__ unsigned int s_msk[16*8];                     // 512 B  [row][word]
  __shared__ float s_logit[128];                           // [wave][row][v]

  const int tid  = threadIdx.x;
  const int w    = tid >> 6;
  const int lane = tid & 63;
  const int l16  = lane & 15;
  const int g4   = lane >> 4;
  const int g8   = g4 * 8;

  const float wx0 = Wx[0], wx1 = Wx[1];

  // ---- zero h/c state ----
  unsigned int* zh = (unsigned int*)s_h;
  unsigned int* zc = (unsigned int*)s_c;
  #pragma unroll
  for (int it=0; it<32; ++it){ zh[tid + it*256] = 0u; zc[tid + it*256] = 0u; }

  // ---- precompute xh for every (traversal slot, batch row) ----
  const float* xg = x + blockIdx.x * 4096;
  #pragma unroll
  for (int k=0; k<16; ++k){
    const int idx = tid + k*256;           // 0..4095
    const int row = idx & 15, slot = idx >> 4;
    const int i = slot >> 4, t = slot & 15;
    const int c   = (i & 1) ? 15 - t : t;
    const int cpc = (i & 1) ? c + 1 : c - 1;
    const float xp = (t > 0) ? xg[row*256 + i*16 + cpc] : 0.f;
    const float xu = (i > 0) ? xg[row*256 + (i-1)*16 + c] : 0.f;
    s_xh[slot*16 + row] = (xp*wx0 + xu*wx1 + 1.f) * 0.5f;
  }
  // ---- mask bits: x>0 at each slot's own grid cell ----
  if (tid < 128){
    const int row = tid >> 3, wd = tid & 7;
    unsigned int m = 0;
    for (int b=0; b<32; ++b){
      const int slot = wd*32 + b, i = slot >> 4, t = slot & 15;
      const int c = (i & 1) ? 15 - t : t;
      if (xg[row*256 + i*16 + c] > 0.f) m |= (1u << b);
    }
    s_msk[row*8 + wd] = m;
  }

  // ---- weight fragments in VGPRs (B-operand layout, all 256 cells) ----
  bf16x8 bh[4], bc[4], bg[4][2];
  #pragma unroll
  for (int s=0;s<4;++s){
    const int n = w*16 + l16, k = s*32 + g8;
    bh[s] = load_w8(Wh  + n*128 + k);   // [0..1]=prev (Wh_p), [2..3]=up (Wh_u)
    bc[s] = load_w8(Wh2 + n*128 + k);
  }
  #pragma unroll
  for (int g=0; g<4; ++g)
    #pragma unroll
    for (int s=0;s<2;++s){
      const int n = g*64 + w*16 + l16, k = s*32 + g8;
      bg[g][s] = load_w8(Whh + n*64 + k);
    }

  const float bfc0 = bfc[0], bfc1 = bfc[1];
  float base_[4], dvec_[4];
  #pragma unroll
  for (int g=0; g<4; ++g){
    const int cg = g*64 + w*16 + l16;
    base_[g] = bih[cg] + bhh[cg] + Wih[cg*2+1];
    dvec_[g] = Wih[cg*2+0] - Wih[cg*2+1];
  }
  const int colw = w*16 + l16;
  const float wf0 = Wfc[colw], wf1 = Wfc[64 + colw];

  // hoisted per-lane LDS offsets (element units)
  const int offA0 = l16*64 + ((     g8) ^ ((l16 & 7) << 3));
  const int offA1 = l16*64 + ((32 + g8) ^ ((l16 & 7) << 3));
  int stW[4];
  #pragma unroll
  for (int r=0;r<4;++r){
    const int row = g4*4 + r;
    stW[r] = row*64 + (colw ^ ((row & 7) << 3));
  }

  float lp = 0.f;
  int aa = 0;

  __syncthreads();

  f32x4 aHuC, aCuC, aHuN, aCuN;   // up-row GEMM contribution, current/next slot

  for (int i=0; i<16; ++i){
    const int dir = i & 1;
    // ---- row prologue: up contribution for t=0 (col where prev row ended) ----
    {
      const int b = (dir ? 15 : 0) << 10;
      f32x4 h0 = {0,0,0,0}, cv = {0,0,0,0};
      bf16x8 ah0 = *(const bf16x8*)(s_h + b + offA0);
      bf16x8 ah1 = *(const bf16x8*)(s_h + b + offA1);
      bf16x8 ac0 = *(const bf16x8*)(s_c + b + offA0);
      bf16x8 ac1 = *(const bf16x8*)(s_c + b + offA1);
      h0 = MFMA(ah0, bh[2], h0); h0 = MFMA(ah1, bh[3], h0);
      cv = MFMA(ac0, bc[2], cv); cv = MFMA(ac1, bc[3], cv);
      aHuC = h0; aCuC = cv;
    }

    for (int t=0; t<16; ++t){
      const int c    = dir ? 15 - t : t;
      const int slot = i*16 + t;

      // ---------- phase 1: h_inter = up(prefetched) + h_prev GEMM ----------
      f32x4 aH = aHuC;
      if (t > 0){
        const int b = (dir ? c + 1 : c - 1) << 10;
        bf16x8 a0 = *(const bf16x8*)(s_h + b + offA0);
        bf16x8 a1 = *(const bf16x8*)(s_h + b + offA1);
        aH = MFMA(a0, bh[0], aH);
        aH = MFMA(a1, bh[1], aH);
      }

      // softmax-finish of previous slot: each wave handles its 4 batch rows
      if (slot > 0 && lane < 4){
        const int R = w*4 + lane;
        float l0 = bfc0, l1 = bfc1;
        #pragma unroll
        for (int ww=0; ww<4; ++ww){
          l0 += s_logit[(ww*16 + R)*2 + 0];
          l1 += s_logit[(ww*16 + R)*2 + 1];
        }
        const float mx  = fmaxf(l0, l1);
        const float lse = mx + __logf(__expf(l0-mx) + __expf(l1-mx));
        const int ps  = slot - 1;
        const int msk = (s_msk[R*8 + (ps >> 5)] >> (ps & 31)) & 1;
        lp += msk ? (l0 - lse) : (l1 - lse);
        aa += msk;
      }

      // hand off h_inter (bf16, swizzled) for the gates GEMM
      #pragma unroll
      for (int r=0;r<4;++r) s_hint[stW[r]] = f2bf(aH[r]);

      __syncthreads();   // B1

      // ---------- phase 2 ----------
      // c_inter: up(prefetched) + c_prev GEMM (only needed by the epilogue)
      f32x4 aC = aCuC;
      if (t > 0){
        const int b = (dir ? c + 1 : c - 1) << 10;
        bf16x8 a0 = *(const bf16x8*)(s_c + b + offA0);
        bf16x8 a1 = *(const bf16x8*)(s_c + b + offA1);
        aC = MFMA(a0, bc[0], aC);
        aC = MFMA(a1, bc[1], aC);
      }

      // gates GEMM, K=64 over h_inter
      const float4 xh4 = *(const float4*)(s_xh + slot*16 + g4*4);
      f32x4 accG[4];
      #pragma unroll
      for (int g=0; g<4; ++g){
        accG[g][0] = base_[g] + xh4.x * dvec_[g];
        accG[g][1] = base_[g] + xh4.y * dvec_[g];
        accG[g][2] = base_[g] + xh4.z * dvec_[g];
        accG[g][3] = base_[g] + xh4.w * dvec_[g];
      }
      bf16x8 ag0 = *(const bf16x8*)(s_hint + offA0);
      bf16x8 ag1 = *(const bf16x8*)(s_hint + offA1);
      #pragma unroll
      for (int g=0; g<4; ++g){
        accG[g] = MFMA(ag0, bg[g][0], accG[g]);
        accG[g] = MFMA(ag1, bg[g][1], accG[g]);
      }

      // prefetch next slot's up-row contribution (reads prev-row columns only;
      // column c(t+1) is untouched by row i until cell t+1) — overlaps epilogue
      if (t < 15){
        const int b = (dir ? 14 - t : t + 1) << 10;
        f32x4 h0 = {0,0,0,0}, cv = {0,0,0,0};
        bf16x8 ah0 = *(const bf16x8*)(s_h + b + offA0);
        bf16x8 ah1 = *(const bf16x8*)(s_h + b + offA1);
        bf16x8 ac0 = *(const bf16x8*)(s_c + b + offA0);
        bf16x8 ac1 = *(const bf16x8*)(s_c + b + offA1);
        h0 = MFMA(ah0, bh[2], h0); h0 = MFMA(ah1, bh[3], h0);
        cv = MFMA(ac0, bc[2], cv); cv = MFMA(ac1, bc[3], cv);
        aHuN = h0; aCuN = cv;
      }

      // epilogue: activations + state write + FC partials
      float p0[4], p1[4];
      const int cb = c << 10;
      #pragma unroll
      for (int r=0;r<4;++r){
        const float ig = accG[0][r], fg = accG[1][r], gg = accG[2][r], og = accG[3][r];
        const float cn = sigm(fg)*aC[r] + sigm(ig)*tanh_(gg);
        const float hn = sigm(og)*tanh_(cn);
        s_h[cb + stW[r]] = f2bf(hn);
        s_c[cb + stW[r]] = f2bf(cn);
        p0[r] = hn * wf0;
        p1[r] = hn * wf1;
      }
      #pragma unroll
      for (int off=1; off<16; off<<=1){
        #pragma unroll
        for (int r=0;r<4;++r){
          p0[r] += __shfl_xor(p0[r], off);
          p1[r] += __shfl_xor(p1[r], off);
        }
      }
      if (l16 == 0){
        #pragma unroll
        for (int r=0;r<4;++r){
          const int row = g4*4 + r;
          s_logit[(w*16 + row)*2 + 0] = p0[r];
          s_logit[(w*16 + row)*2 + 1] = p1[r];
        }
      }

      aHuC = aHuN; aCuC = aCuN;
      __syncthreads();   // B2
    }
  }

  // finish slot 255 (cell (15,0)), rec fix, store
  if (lane < 4){
    const int R = w*4 + lane;
    float l0 = bfc0, l1 = bfc1;
    #pragma unroll
    for (int ww=0; ww<4; ++ww){
      l0 += s_logit[(ww*16 + R)*2 + 0];
      l1 += s_logit[(ww*16 + R)*2 + 1];
    }
    const float mx  = fmaxf(l0, l1);
    const float lse = mx + __logf(__expf(l0-mx) + __expf(l1-mx));
    const int msk = (s_msk[R*8 + 7] >> 31) & 1;
    const float contrib = msk ? (l0 - lse) : (l1 - lse);
    lp += contrib; aa += msk;
    if (aa == 1 && msk) lp -= contrib;   // factor = 1 - mask[15,0] when aa==1
    out[blockIdx.x*16 + R] = lp;
  }
}

extern "C" void kernel_launch(void* const* d_in, const int* in_sizes, int n_in,
                              void* d_out, int out_size, void* d_ws, size_t ws_size,
                              hipStream_t stream) {
  const float* x   = (const float*)d_in[0];
  const float* Wx  = (const float*)d_in[1];
  const float* Wh  = (const float*)d_in[2];
  const float* Wh2 = (const float*)d_in[3];
  const float* Wih = (const float*)d_in[4];
  const float* Whh = (const float*)d_in[5];
  const float* bih = (const float*)d_in[6];
  const float* bhh = (const float*)d_in[7];
  const float* Wfc = (const float*)d_in[8];
  const float* bfc = (const float*)d_in[9];
  float* out = (float*)d_out;
  lstm2d_kernel<<<dim3(256), dim3(256), 0, stream>>>(
      x, Wx, Wh, Wh2, Wih, Whh, bih, bhh, Wfc, bfc, out);
}